// Round 11
// baseline (150.907 us; speedup 1.0000x reference)
//
#include <hip/hip_runtime.h>
#include <math.h>

#define B 64
#define H 512
#define V 50257
#define M 200
#define H2 1024
#define H3 1536
#define H4 2048
#define NB 786             // ceil(V/64) = out-GEMM blocks

typedef short short8 __attribute__((ext_vector_type(8)));
typedef float f32x4 __attribute__((ext_vector_type(4)));
typedef const __attribute__((address_space(1))) unsigned int u32g;
typedef __attribute__((address_space(3))) unsigned int u32l;

__device__ __forceinline__ float sigf(float x) { return 1.f / (1.f + expf(-x)); }

// f32 -> bf16 (RNE) as raw short
__device__ __forceinline__ short bf16c(float f) {
  unsigned u = __builtin_bit_cast(unsigned, f);
  unsigned r = u + 0x7fffu + ((u >> 16) & 1u);
  return (short)(r >> 16);
}

__device__ __forceinline__ short8 cvt8(float4 a, float4 b) {
  short8 w;
  w[0] = bf16c(a.x); w[1] = bf16c(a.y); w[2] = bf16c(a.z); w[3] = bf16c(a.w);
  w[4] = bf16c(b.x); w[5] = bf16c(b.y); w[6] = bf16c(b.z); w[7] = bf16c(b.w);
  return w;
}

// ---------------- K1: A_lstm[b][k] = [relu(emb[ids[b]]) | ctx[b] | h0[b]] (bf16) ----------------
__global__ __launch_bounds__(256) void k_build_A(
    const float* __restrict__ emb, const float* __restrict__ ctx,
    const float* __restrict__ h0, const int* __restrict__ ids,
    short* __restrict__ A) {
  int k = blockIdx.x * 256 + threadIdx.x;   // 0..1535
  int b = blockIdx.y;
  float v;
  if (k < 512) {
    v = emb[(size_t)ids[b] * H + k];
    v = v > 0.f ? v : 0.f;
  } else if (k < 1024) {
    v = ctx[b * H + (k - 512)];
  } else {
    v = h0[b * H + (k - 1024)];
  }
  A[b * H3 + k] = bf16c(v);
}

// ---------------- K2: LSTM gates via MFMA. grid 128 (16 j-cols each), 4 waves k-split ----------------
__global__ __launch_bounds__(256) void k_lstm_gates_mfma(
    const short* __restrict__ A, const float* __restrict__ W_ih,
    const float* __restrict__ W_hh, const float* __restrict__ b_ih,
    const float* __restrict__ b_hh, float* __restrict__ gates) {
  __shared__ float sred[3][64][16];
  const int tid = threadIdx.x;
  const int lane = tid & 63, wid = tid >> 6;
  const int col = lane & 15, g = lane >> 4;
  const int j = blockIdx.x * 16 + col;      // gate-row 0..2047
  const int kbase = wid * 384;

  f32x4 acc[4];
  #pragma unroll
  for (int t = 0; t < 4; ++t) acc[t] = (f32x4)(0.f);

  #pragma unroll 2
  for (int it = 0; it < 12; ++it) {
    int k0 = kbase + it * 32;
    const float* wp;
    if (k0 < 1024) wp = W_ih + (size_t)j * H2 + k0 + g * 8;
    else           wp = W_hh + (size_t)j * H + (k0 - 1024) + g * 8;
    float4 wa = *(const float4*)wp;
    float4 wb = *(const float4*)(wp + 4);
    short8 bf = cvt8(wa, wb);
    #pragma unroll
    for (int t = 0; t < 4; ++t) {
      short8 af = *(const short8*)(A + (size_t)(col + t * 16) * H3 + k0 + g * 8);
      acc[t] = __builtin_amdgcn_mfma_f32_16x16x32_bf16(af, bf, acc[t], 0, 0, 0);
    }
  }

  if (wid) {
    #pragma unroll
    for (int t = 0; t < 4; ++t)
      #pragma unroll
      for (int r = 0; r < 4; ++r) sred[wid - 1][lane][t * 4 + r] = acc[t][r];
  }
  __syncthreads();
  if (wid == 0) {
    float bias = b_ih[j] + b_hh[j];
    #pragma unroll
    for (int t = 0; t < 4; ++t)
      #pragma unroll
      for (int r = 0; r < 4; ++r) {
        float s = acc[t][r] + sred[0][lane][t * 4 + r] + sred[1][lane][t * 4 + r] +
                  sred[2][lane][t * 4 + r];
        int brow = t * 16 + g * 4 + r;
        gates[brow * H4 + j] = s + bias;
      }
  }
}

// ---------------- K3: LSTM cell elementwise (+ h1 bf16 copy) ----------------
__global__ __launch_bounds__(256) void k_lstm_cell(
    const float* __restrict__ gates, const float* __restrict__ c0,
    float* __restrict__ h1, float* __restrict__ c1, short* __restrict__ h1bf) {
  int idx = blockIdx.x * 256 + threadIdx.x;  // B*H
  int b = idx >> 9, h = idx & 511;
  const float* g = gates + b * H4;
  float gi = g[h], gf = g[H + h], gg = g[2 * H + h], go = g[3 * H + h];
  float c = sigf(gf) * c0[idx] + sigf(gi) * tanhf(gg);
  c1[idx] = c;
  float hv = sigf(go) * tanhf(c);
  h1[idx] = hv;
  h1bf[idx] = bf16c(hv);
}

// ---------------- K4: attn[b][m] = m_emb[mt[m][b]] . h1[b] ----------------
__global__ __launch_bounds__(256) void k_attn_scores(
    const float* __restrict__ m_emb, const int* __restrict__ mt,
    const float* __restrict__ h1, float* __restrict__ attn) {
  int wave = (blockIdx.x * 256 + threadIdx.x) >> 6;
  int lane = threadIdx.x & 63;
  int m = wave >> 6, b = wave & 63;
  int row = mt[m * B + b];
  const float4* e = (const float4*)(m_emb + (size_t)row * H);
  const float4* hv = (const float4*)(h1 + b * H);
  float4 a0 = e[lane], a1 = e[64 + lane];
  float4 b0 = hv[lane], b1 = hv[64 + lane];
  float acc = a0.x * b0.x + a0.y * b0.y + a0.z * b0.z + a0.w * b0.w +
              a1.x * b1.x + a1.y * b1.y + a1.z * b1.z + a1.w * b1.w;
  for (int off = 32; off > 0; off >>= 1) acc += __shfl_down(acc, off);
  if (lane == 0) attn[b * M + m] = acc;
}

// ---------------- K5: attn2 = attn @ attn_W^T + attn_b; log_softmax ----------------
__global__ __launch_bounds__(256) void k_attn_lin_lsm(
    const float* __restrict__ attn, const float* __restrict__ attn_W,
    const float* __restrict__ attn_b, float* __restrict__ attn_d) {
  __shared__ float arow[M];
  __shared__ float vals[256];
  __shared__ float red[256];
  int b = blockIdx.x, tid = threadIdx.x;
  if (tid < M) arow[tid] = attn[b * M + tid];
  __syncthreads();
  float v = -1e30f;
  if (tid < M) {
    const float* w = attn_W + tid * M;
    float a0 = attn_b[tid], a1 = 0.f;
    for (int m = 0; m < M; m += 2) {
      a0 = fmaf(arow[m], w[m], a0);
      a1 = fmaf(arow[m + 1], w[m + 1], a1);
    }
    v = a0 + a1;
  }
  vals[tid] = v;
  red[tid] = v;
  __syncthreads();
  for (int off = 128; off > 0; off >>= 1) {
    if (tid < off) red[tid] = fmaxf(red[tid], red[tid + off]);
    __syncthreads();
  }
  float mx = red[0];
  __syncthreads();
  red[tid] = (tid < M) ? expf(vals[tid] - mx) : 0.f;
  __syncthreads();
  for (int off = 128; off > 0; off >>= 1) {
    if (tid < off) red[tid] += red[tid + off];
    __syncthreads();
  }
  float lse = mx + logf(red[0]);
  if (tid < M) attn_d[b * M + tid] = vals[tid] - lse;
}

// ---------------- K6: memory_context partial sums over 4 m-chunks of 50 ----------------
__global__ __launch_bounds__(256) void k_mem_ctx_partial(
    const float* __restrict__ c_emb, const int* __restrict__ mt,
    const float* __restrict__ attn_d, float* __restrict__ mcp) {
  int b = blockIdx.x;     // 64
  int chunk = blockIdx.y; // 4
  int tid = threadIdx.x;  // 256
  __shared__ int rows[50];
  __shared__ float w[50];
  if (tid < 50) {
    int m = chunk * 50 + tid;
    rows[tid] = mt[m * B + b];
    w[tid] = attn_d[b * M + m];
  }
  __syncthreads();
  float acc0 = 0.f, acc1 = 0.f;
  #pragma unroll 5
  for (int i = 0; i < 50; ++i) {
    const float* e = c_emb + (size_t)rows[i] * H;
    acc0 = fmaf(w[i], e[tid], acc0);
    acc1 = fmaf(w[i], e[256 + tid], acc1);
  }
  mcp[(chunk * B + b) * H + tid] = acc0;
  mcp[(chunk * B + b) * H + 256 + tid] = acc1;
}

// K6b: reduce partials -> mc bf16
__global__ __launch_bounds__(256) void k_mem_ctx_reduce(
    const float* __restrict__ mcp, short* __restrict__ mcbf) {
  int idx = blockIdx.x * 256 + threadIdx.x;  // B*H
  float s = 0.f;
  for (int c = 0; c < 4; ++c) s += mcp[c * (B * H) + idx];
  mcbf[idx] = bf16c(s);
}

// ---------------- K7: GRU gates via MFMA. grid 192: half (gi/gh) x 96 col-tiles ----------------
__global__ __launch_bounds__(256) void k_gru_gates_mfma(
    const short* __restrict__ mcbf, const short* __restrict__ h1bf,
    const float* __restrict__ W_ih, const float* __restrict__ W_hh,
    const float* __restrict__ b_ih, const float* __restrict__ b_hh,
    float* __restrict__ gi, float* __restrict__ gh) {
  __shared__ float sred[3][64][16];
  const int tid = threadIdx.x;
  const int lane = tid & 63, wid = tid >> 6;
  const int col = lane & 15, g = lane >> 4;
  const int half = blockIdx.x / 96;
  const int j = (blockIdx.x % 96) * 16 + col;   // 0..1535
  const short* A = half ? h1bf : mcbf;
  const float* W = half ? W_hh : W_ih;
  const float* bias = half ? b_hh : b_ih;
  float* out = half ? gh : gi;
  const int kbase = wid * 128;

  f32x4 acc[4];
  #pragma unroll
  for (int t = 0; t < 4; ++t) acc[t] = (f32x4)(0.f);

  #pragma unroll
  for (int it = 0; it < 4; ++it) {
    int k0 = kbase + it * 32;
    const float* wp = W + (size_t)j * H + k0 + g * 8;
    float4 wa = *(const float4*)wp;
    float4 wb = *(const float4*)(wp + 4);
    short8 bf = cvt8(wa, wb);
    #pragma unroll
    for (int t = 0; t < 4; ++t) {
      short8 af = *(const short8*)(A + (size_t)(col + t * 16) * H + k0 + g * 8);
      acc[t] = __builtin_amdgcn_mfma_f32_16x16x32_bf16(af, bf, acc[t], 0, 0, 0);
    }
  }

  if (wid) {
    #pragma unroll
    for (int t = 0; t < 4; ++t)
      #pragma unroll
      for (int r = 0; r < 4; ++r) sred[wid - 1][lane][t * 4 + r] = acc[t][r];
  }
  __syncthreads();
  if (wid == 0) {
    float bv = bias[j];
    #pragma unroll
    for (int t = 0; t < 4; ++t)
      #pragma unroll
      for (int r = 0; r < 4; ++r) {
        float s = acc[t][r] + sred[0][lane][t * 4 + r] + sred[1][lane][t * 4 + r] +
                  sred[2][lane][t * 4 + r];
        int brow = t * 16 + g * 4 + r;
        out[brow * H3 + j] = s + bv;
      }
  }
}

// ---------------- K8: GRU combine + build A (bf16) = [mb, ctx] ----------------
__global__ __launch_bounds__(256) void k_gru_combine(
    const float* __restrict__ gi, const float* __restrict__ gh,
    const float* __restrict__ h1, const float* __restrict__ ctx,
    short* __restrict__ Abf) {
  int idx = blockIdx.x * 256 + threadIdx.x;  // B*H
  int b = idx >> 9, h = idx & 511;
  const float* gib = gi + b * H3;
  const float* ghb = gh + b * H3;
  float r = sigf(gib[h] + ghb[h]);
  float z = sigf(gib[H + h] + ghb[H + h]);
  float n = tanhf(gib[2 * H + h] + r * ghb[2 * H + h]);
  float mb = (1.f - z) * n + z * h1[idx];
  Abf[b * H2 + h] = bf16c(mb);
  Abf[b * H2 + H + h] = bf16c(ctx[idx]);
}

// ---------------- K8b: convert out_W f32 -> bf16 (103 MB, L3-resident) ----------------
__global__ __launch_bounds__(256) void k_wcvt(
    const float* __restrict__ W, short* __restrict__ Wbf) {
  const int total = (V * H2) / 8;   // 6,432,896 groups of 8
  for (int i = blockIdx.x * 256 + threadIdx.x; i < total; i += 2048 * 256) {
    float4 a = *(const float4*)(W + (size_t)i * 8);
    float4 b = *(const float4*)(W + (size_t)i * 8 + 4);
    *(short8*)(Wbf + (size_t)i * 8) = cvt8(a, b);
  }
}

// ---------------- K9: logits = A @ Wbf^T + bias — global_load_lds + counted-vmcnt pipeline ----------------
// grid NB=786 x 512 thr (8 waves). Per block: 64 vocab x 64 batch, BK=64, 16 K-steps.
// Staging: 1 global_load_lds(16B) per thread per tile per matrix; LDS dest linear (tid*16B),
// global source pre-swizzled chunk^(row&7) within each 128B row-span (same cache line, m173).
// 3 LDS stage-buffers; schedule (m201 ledger): STAGE(kt+2) -> COMPUTE(kt) -> vmcnt(2) -> raw
// s_barrier. vmcnt never drains to 0 in the loop => 2 stages (4 loads/thread) stay in flight
// across barriers. No cvt in this kernel (W pre-converted by k_wcvt).
__global__ __launch_bounds__(512) void k_out_gemm_mfma(
    const short* __restrict__ Abf, const short* __restrict__ Wbf,
    const float* __restrict__ bias, float* __restrict__ out,
    float* __restrict__ pm, float* __restrict__ ps) {
  __shared__ short8 Wl[3][512];   // 3 stages x 64 rows x 8 chunks(16B) = 24 KB
  __shared__ short8 Al[3][512];   // 24 KB
  __shared__ float spm[8][32];
  __shared__ float sps[8][32];
  const int tid = threadIdx.x;
  const int lane = tid & 63, wid = tid >> 6;
  const int v0 = blockIdx.x * 64;

  // staging source: thread fills LDS slot tid (row sr=tid>>3, chunk tid&7);
  // source chunk = (tid&7)^(sr&7)  (XOR involution; read side applies same XOR)
  const int sr = tid >> 3;
  const int sc = (tid & 7) ^ (sr & 7);
  int vr = v0 + sr; if (vr >= V) vr = V - 1;
  const short* wsrc = Wbf + (size_t)vr * H2 + sc * 8;
  const short* asrc = Abf + (size_t)sr * H2 + sc * 8;

  // compute role
  const int col = lane & 15, g = lane >> 4;
  const int ct = wid & 3, bh = wid >> 2;
  const int wrow = ct * 16 + col;
  const int a0r = bh * 32 + col;
  const int a1r = a0r + 16;

  f32x4 acc0 = (f32x4)(0.f), acc1 = (f32x4)(0.f);

#define STAGE(s, kt)                                                          \
  { __builtin_amdgcn_global_load_lds((u32g*)(wsrc + (kt) * 64),               \
        (u32l*)&Wl[s][tid], 16, 0, 0);                                        \
    __builtin_amdgcn_global_load_lds((u32g*)(asrc + (kt) * 64),               \
        (u32l*)&Al[s][tid], 16, 0, 0); }

#define COMPUTE(s)                                                            \
  { _Pragma("unroll") for (int kw = 0; kw < 2; ++kw) {                        \
      int c = kw * 4 + g;                                                     \
      short8 bf  = Wl[s][wrow * 8 + (c ^ (wrow & 7))];                        \
      short8 af0 = Al[s][a0r * 8 + (c ^ (a0r & 7))];                          \
      short8 af1 = Al[s][a1r * 8 + (c ^ (a1r & 7))];                          \
      acc0 = __builtin_amdgcn_mfma_f32_16x16x32_bf16(af0, bf, acc0, 0, 0, 0); \
      acc1 = __builtin_amdgcn_mfma_f32_16x16x32_bf16(af1, bf, acc1, 0, 0, 0); \
    } }

  // prologue: stages 0,1 in flight; wait stage 0 only
  STAGE(0, 0);
  STAGE(1, 1);
  asm volatile("s_waitcnt vmcnt(2)" ::: "memory");
  __builtin_amdgcn_s_barrier();

  #pragma unroll
  for (int kt = 0; kt < 16; ++kt) {
    const int cb = kt % 3;
    if (kt + 2 < 16) STAGE((kt + 2) % 3, kt + 2);
    COMPUTE(cb);
    if (kt + 1 < 16) {
      if (kt + 2 < 16) { asm volatile("s_waitcnt vmcnt(2)" ::: "memory"); }
      else             { asm volatile("s_waitcnt vmcnt(0)" ::: "memory"); }
      __builtin_amdgcn_s_barrier();
    }
  }
#undef STAGE
#undef COMPUTE

  // epilogue: store + fused per-block LSE partials
  const int v = v0 + ct * 16 + col;
  const float bv = (v < V) ? bias[v] : 0.f;
  #pragma unroll
  for (int ai = 0; ai < 2; ++ai) {
    f32x4 a = ai ? acc1 : acc0;
    #pragma unroll
    for (int r = 0; r < 4; ++r) {
      int b = bh * 32 + ai * 16 + g * 4 + r;
      float x = a[r] + bv;
      if (v < V) out[(size_t)b * V + v] = x;
      float xm = (v < V) ? x : -1e30f;
      float mx = xm;
      #pragma unroll
      for (int off = 1; off < 16; off <<= 1) mx = fmaxf(mx, __shfl_xor(mx, off));
      float e = (v < V) ? expf(xm - mx) : 0.f;
      #pragma unroll
      for (int off = 1; off < 16; off <<= 1) e += __shfl_xor(e, off);
      if (col == 0) {
        spm[wid][ai * 16 + g * 4 + r] = mx;
        sps[wid][ai * 16 + g * 4 + r] = e;
      }
    }
  }
  __syncthreads();
  if (tid < 64) {
    int b = tid;
    int wbase = (b >> 5) * 4;
    int bl = b & 31;
    float m = spm[wbase][bl], s = sps[wbase][bl];
    #pragma unroll
    for (int w = 1; w < 4; ++w) {
      float m2 = spm[wbase + w][bl], s2 = sps[wbase + w][bl];
      float nm = fmaxf(m, m2);
      s = s * expf(m - nm) + s2 * expf(m2 - nm);
      m = nm;
    }
    pm[(size_t)b * NB + blockIdx.x] = m;
    ps[(size_t)b * NB + blockIdx.x] = s;
  }
}

// ---------------- K10: combine partials -> lse[b] ----------------
__global__ __launch_bounds__(256) void k_lsm_finalize(
    const float* __restrict__ pm, const float* __restrict__ ps,
    float* __restrict__ lse) {
  int b = blockIdx.x, tid = threadIdx.x;
  float m = -1e30f, s = 0.f;
  for (int gq = tid; gq < NB; gq += 256) {
    float m2 = pm[(size_t)b * NB + gq], s2 = ps[(size_t)b * NB + gq];
    float nm = fmaxf(m, m2);
    s = s * expf(m - nm) + s2 * expf(m2 - nm);
    m = nm;
  }
  __shared__ float sm[256], ss[256];
  sm[tid] = m; ss[tid] = s;
  __syncthreads();
  for (int off = 128; off > 0; off >>= 1) {
    if (tid < off) {
      float m1 = sm[tid], s1 = ss[tid];
      float m2 = sm[tid + off], s2 = ss[tid + off];
      float nm = fmaxf(m1, m2);
      sm[tid] = nm;
      ss[tid] = s1 * expf(m1 - nm) + s2 * expf(m2 - nm);
    }
    __syncthreads();
  }
  if (tid == 0) lse[b] = sm[0] + logf(ss[0]);
}

// ---------------- K11: out -= lse[b]. grid (50, B) ----------------
__global__ __launch_bounds__(256) void k_lsm_apply(
    float* __restrict__ out, const float* __restrict__ lse) {
  int b = blockIdx.y, tid = threadIdx.x;
  float l = lse[b];
  int v = blockIdx.x * 1024 + tid * 4;
  float* row = out + (size_t)b * V;
  if (v + 3 < V) {
    float4 x = *(const float4*)(row + v);
    x.x -= l; x.y -= l; x.z -= l; x.w -= l;
    *(float4*)(row + v) = x;
  } else {
    for (int i = 0; i < 4 && v + i < V; ++i) row[v + i] -= l;
  }
}

extern "C" void kernel_launch(void* const* d_in, const int* in_sizes, int n_in,
                              void* d_out, int out_size, void* d_ws, size_t ws_size,
                              hipStream_t stream) {
  const float* h0    = (const float*)d_in[0];
  const float* c0    = (const float*)d_in[1];
  const float* ctx   = (const float*)d_in[2];
  const float* emb   = (const float*)d_in[3];
  const float* m_emb = (const float*)d_in[4];
  const float* c_emb = (const float*)d_in[5];
  const float* lWih  = (const float*)d_in[6];
  const float* lWhh  = (const float*)d_in[7];
  const float* lbih  = (const float*)d_in[8];
  const float* lbhh  = (const float*)d_in[9];
  const float* gWih  = (const float*)d_in[10];
  const float* gWhh  = (const float*)d_in[11];
  const float* gbih  = (const float*)d_in[12];
  const float* gbhh  = (const float*)d_in[13];
  const float* aW    = (const float*)d_in[14];
  const float* ab    = (const float*)d_in[15];
  const float* oW    = (const float*)d_in[16];
  const float* ob    = (const float*)d_in[17];
  const int* ids     = (const int*)d_in[18];
  const int* mt      = (const int*)d_in[19];

  float* out = (float*)d_out;
  float* h1  = out + (size_t)B * V;
  float* c1  = h1 + B * H;

  // Workspace layout — offsets in FLOAT units; bf16 buffers counted as shorts/2 floats.
  float* ws    = (float*)d_ws;
  short* Albf  = (short*)ws;                   // 64*1536 shorts = 49152 fl
  float* gates = ws + 49152;                   // B*H4 = 131072 fl
  short* h1bf  = (short*)(gates + B * H4);     // 64*512 shorts = 16384 fl
  float* attn  = gates + B * H4 + 16384;       // B*M = 12800 fl
  float* attnd = attn + B * M;                 // 12800 fl
  float* mcp   = attnd + B * M;                // 4*B*H = 131072 fl
  short* mcbf  = (short*)(mcp + 4 * B * H);    // 64*512 shorts = 16384 fl
  float* gi    = mcp + 4 * B * H + 16384;      // B*H3 = 98304 fl
  float* gh    = gi + B * H3;                  // 98304 fl
  short* Abf   = (short*)(gh + B * H3);        // 64*1024 shorts = 32768 fl
  float* pm    = gh + B * H3 + 32768;          // B*NB = 50304 fl
  float* ps    = pm + (size_t)B * NB;          // 50304 fl
  float* lse   = ps + (size_t)B * NB;          // 64 fl
  short* Wbf   = (short*)(lse + 64);           // V*H2 shorts = 103 MB

  dim3 g1(6, B);
  k_build_A<<<g1, 256, 0, stream>>>(emb, ctx, h0, ids, Albf);
  k_lstm_gates_mfma<<<128, 256, 0, stream>>>(Albf, lWih, lWhh, lbih, lbhh, gates);
  k_lstm_cell<<<(B * H) / 256, 256, 0, stream>>>(gates, c0, h1, c1, h1bf);
  k_attn_scores<<<(M * B) / 4, 256, 0, stream>>>(m_emb, mt, h1, attn);
  k_attn_lin_lsm<<<B, 256, 0, stream>>>(attn, aW, ab, attnd);
  dim3 g6(B, 4);
  k_mem_ctx_partial<<<g6, 256, 0, stream>>>(c_emb, mt, attnd, mcp);
  k_mem_ctx_reduce<<<(B * H) / 256, 256, 0, stream>>>(mcp, mcbf);
  k_gru_gates_mfma<<<192, 256, 0, stream>>>(mcbf, h1bf, gWih, gWhh, gbih, gbhh, gi, gh);
  k_gru_combine<<<(B * H) / 256, 256, 0, stream>>>(gi, gh, h1, ctx, Abf);
  k_wcvt<<<2048, 256, 0, stream>>>(oW, Wbf);
  k_out_gemm_mfma<<<NB, 512, 0, stream>>>(Abf, Wbf, ob, out, pm, ps);
  k_lsm_finalize<<<B, 256, 0, stream>>>(pm, ps, lse);
  dim3 g11(50, B);
  k_lsm_apply<<<g11, 256, 0, stream>>>(out, lse);
}

// Round 12
// 117.440 us; speedup vs baseline: 1.2850x; 1.2850x over previous
//
#include <hip/hip_runtime.h>
#include <math.h>

#define B 64
#define H 512
#define V 50257
#define M 200
#define H2 1024
#define H3 1536
#define H4 2048
#define NB 786             // ceil(V/64) = out-GEMM blocks

typedef short short8 __attribute__((ext_vector_type(8)));
typedef float f32x4 __attribute__((ext_vector_type(4)));

__device__ __forceinline__ float sigf(float x) { return 1.f / (1.f + expf(-x)); }

// f32 -> bf16 (RNE) as raw short
__device__ __forceinline__ short bf16c(float f) {
  unsigned u = __builtin_bit_cast(unsigned, f);
  unsigned r = u + 0x7fffu + ((u >> 16) & 1u);
  return (short)(r >> 16);
}

__device__ __forceinline__ short8 cvt8(float4 a, float4 b) {
  short8 w;
  w[0] = bf16c(a.x); w[1] = bf16c(a.y); w[2] = bf16c(a.z); w[3] = bf16c(a.w);
  w[4] = bf16c(b.x); w[5] = bf16c(b.y); w[6] = bf16c(b.z); w[7] = bf16c(b.w);
  return w;
}

// ---------------- K1: A_lstm[b][k] = [relu(emb[ids[b]]) | ctx[b] | h0[b]] (bf16) ----------------
__global__ __launch_bounds__(256) void k_build_A(
    const float* __restrict__ emb, const float* __restrict__ ctx,
    const float* __restrict__ h0, const int* __restrict__ ids,
    short* __restrict__ A) {
  int k = blockIdx.x * 256 + threadIdx.x;   // 0..1535
  int b = blockIdx.y;
  float v;
  if (k < 512) {
    v = emb[(size_t)ids[b] * H + k];
    v = v > 0.f ? v : 0.f;
  } else if (k < 1024) {
    v = ctx[b * H + (k - 512)];
  } else {
    v = h0[b * H + (k - 1024)];
  }
  A[b * H3 + k] = bf16c(v);
}

// ---------------- K2: LSTM gates via MFMA. grid 128 (16 j-cols each), 4 waves k-split ----------------
__global__ __launch_bounds__(256) void k_lstm_gates_mfma(
    const short* __restrict__ A, const float* __restrict__ W_ih,
    const float* __restrict__ W_hh, const float* __restrict__ b_ih,
    const float* __restrict__ b_hh, float* __restrict__ gates) {
  __shared__ float sred[3][64][16];
  const int tid = threadIdx.x;
  const int lane = tid & 63, wid = tid >> 6;
  const int col = lane & 15, g = lane >> 4;
  const int j = blockIdx.x * 16 + col;      // gate-row 0..2047
  const int kbase = wid * 384;

  f32x4 acc[4];
  #pragma unroll
  for (int t = 0; t < 4; ++t) acc[t] = (f32x4)(0.f);

  #pragma unroll 2
  for (int it = 0; it < 12; ++it) {
    int k0 = kbase + it * 32;
    const float* wp;
    if (k0 < 1024) wp = W_ih + (size_t)j * H2 + k0 + g * 8;
    else           wp = W_hh + (size_t)j * H + (k0 - 1024) + g * 8;
    float4 wa = *(const float4*)wp;
    float4 wb = *(const float4*)(wp + 4);
    short8 bf = cvt8(wa, wb);
    #pragma unroll
    for (int t = 0; t < 4; ++t) {
      short8 af = *(const short8*)(A + (size_t)(col + t * 16) * H3 + k0 + g * 8);
      acc[t] = __builtin_amdgcn_mfma_f32_16x16x32_bf16(af, bf, acc[t], 0, 0, 0);
    }
  }

  if (wid) {
    #pragma unroll
    for (int t = 0; t < 4; ++t)
      #pragma unroll
      for (int r = 0; r < 4; ++r) sred[wid - 1][lane][t * 4 + r] = acc[t][r];
  }
  __syncthreads();
  if (wid == 0) {
    float bias = b_ih[j] + b_hh[j];
    #pragma unroll
    for (int t = 0; t < 4; ++t)
      #pragma unroll
      for (int r = 0; r < 4; ++r) {
        float s = acc[t][r] + sred[0][lane][t * 4 + r] + sred[1][lane][t * 4 + r] +
                  sred[2][lane][t * 4 + r];
        int brow = t * 16 + g * 4 + r;
        gates[brow * H4 + j] = s + bias;
      }
  }
}

// ---------------- K3: LSTM cell elementwise (+ h1 bf16 copy) ----------------
__global__ __launch_bounds__(256) void k_lstm_cell(
    const float* __restrict__ gates, const float* __restrict__ c0,
    float* __restrict__ h1, float* __restrict__ c1, short* __restrict__ h1bf) {
  int idx = blockIdx.x * 256 + threadIdx.x;  // B*H
  int b = idx >> 9, h = idx & 511;
  const float* g = gates + b * H4;
  float gi = g[h], gf = g[H + h], gg = g[2 * H + h], go = g[3 * H + h];
  float c = sigf(gf) * c0[idx] + sigf(gi) * tanhf(gg);
  c1[idx] = c;
  float hv = sigf(go) * tanhf(c);
  h1[idx] = hv;
  h1bf[idx] = bf16c(hv);
}

// ---------------- K4: attn[b][m] = m_emb[mt[m][b]] . h1[b] ----------------
__global__ __launch_bounds__(256) void k_attn_scores(
    const float* __restrict__ m_emb, const int* __restrict__ mt,
    const float* __restrict__ h1, float* __restrict__ attn) {
  int wave = (blockIdx.x * 256 + threadIdx.x) >> 6;
  int lane = threadIdx.x & 63;
  int m = wave >> 6, b = wave & 63;
  int row = mt[m * B + b];
  const float4* e = (const float4*)(m_emb + (size_t)row * H);
  const float4* hv = (const float4*)(h1 + b * H);
  float4 a0 = e[lane], a1 = e[64 + lane];
  float4 b0 = hv[lane], b1 = hv[64 + lane];
  float acc = a0.x * b0.x + a0.y * b0.y + a0.z * b0.z + a0.w * b0.w +
              a1.x * b1.x + a1.y * b1.y + a1.z * b1.z + a1.w * b1.w;
  for (int off = 32; off > 0; off >>= 1) acc += __shfl_down(acc, off);
  if (lane == 0) attn[b * M + m] = acc;
}

// ---------------- K5: attn2 = attn @ attn_W^T + attn_b; log_softmax ----------------
__global__ __launch_bounds__(256) void k_attn_lin_lsm(
    const float* __restrict__ attn, const float* __restrict__ attn_W,
    const float* __restrict__ attn_b, float* __restrict__ attn_d) {
  __shared__ float arow[M];
  __shared__ float vals[256];
  __shared__ float red[256];
  int b = blockIdx.x, tid = threadIdx.x;
  if (tid < M) arow[tid] = attn[b * M + tid];
  __syncthreads();
  float v = -1e30f;
  if (tid < M) {
    const float* w = attn_W + tid * M;
    float a0 = attn_b[tid], a1 = 0.f;
    for (int m = 0; m < M; m += 2) {
      a0 = fmaf(arow[m], w[m], a0);
      a1 = fmaf(arow[m + 1], w[m + 1], a1);
    }
    v = a0 + a1;
  }
  vals[tid] = v;
  red[tid] = v;
  __syncthreads();
  for (int off = 128; off > 0; off >>= 1) {
    if (tid < off) red[tid] = fmaxf(red[tid], red[tid + off]);
    __syncthreads();
  }
  float mx = red[0];
  __syncthreads();
  red[tid] = (tid < M) ? expf(vals[tid] - mx) : 0.f;
  __syncthreads();
  for (int off = 128; off > 0; off >>= 1) {
    if (tid < off) red[tid] += red[tid + off];
    __syncthreads();
  }
  float lse = mx + logf(red[0]);
  if (tid < M) attn_d[b * M + tid] = vals[tid] - lse;
}

// ---------------- K6: memory_context partial sums over 4 m-chunks of 50 ----------------
__global__ __launch_bounds__(256) void k_mem_ctx_partial(
    const float* __restrict__ c_emb, const int* __restrict__ mt,
    const float* __restrict__ attn_d, float* __restrict__ mcp) {
  int b = blockIdx.x;     // 64
  int chunk = blockIdx.y; // 4
  int tid = threadIdx.x;  // 256
  __shared__ int rows[50];
  __shared__ float w[50];
  if (tid < 50) {
    int m = chunk * 50 + tid;
    rows[tid] = mt[m * B + b];
    w[tid] = attn_d[b * M + m];
  }
  __syncthreads();
  float acc0 = 0.f, acc1 = 0.f;
  #pragma unroll 5
  for (int i = 0; i < 50; ++i) {
    const float* e = c_emb + (size_t)rows[i] * H;
    acc0 = fmaf(w[i], e[tid], acc0);
    acc1 = fmaf(w[i], e[256 + tid], acc1);
  }
  mcp[(chunk * B + b) * H + tid] = acc0;
  mcp[(chunk * B + b) * H + 256 + tid] = acc1;
}

// K6b: reduce partials -> mc bf16
__global__ __launch_bounds__(256) void k_mem_ctx_reduce(
    const float* __restrict__ mcp, short* __restrict__ mcbf) {
  int idx = blockIdx.x * 256 + threadIdx.x;  // B*H
  float s = 0.f;
  for (int c = 0; c < 4; ++c) s += mcp[c * (B * H) + idx];
  mcbf[idx] = bf16c(s);
}

// ---------------- K7: GRU gates via MFMA. grid 192: half (gi/gh) x 96 col-tiles ----------------
__global__ __launch_bounds__(256) void k_gru_gates_mfma(
    const short* __restrict__ mcbf, const short* __restrict__ h1bf,
    const float* __restrict__ W_ih, const float* __restrict__ W_hh,
    const float* __restrict__ b_ih, const float* __restrict__ b_hh,
    float* __restrict__ gi, float* __restrict__ gh) {
  __shared__ float sred[3][64][16];
  const int tid = threadIdx.x;
  const int lane = tid & 63, wid = tid >> 6;
  const int col = lane & 15, g = lane >> 4;
  const int half = blockIdx.x / 96;
  const int j = (blockIdx.x % 96) * 16 + col;   // 0..1535
  const short* A = half ? h1bf : mcbf;
  const float* W = half ? W_hh : W_ih;
  const float* bias = half ? b_hh : b_ih;
  float* out = half ? gh : gi;
  const int kbase = wid * 128;

  f32x4 acc[4];
  #pragma unroll
  for (int t = 0; t < 4; ++t) acc[t] = (f32x4)(0.f);

  #pragma unroll
  for (int it = 0; it < 4; ++it) {
    int k0 = kbase + it * 32;
    const float* wp = W + (size_t)j * H + k0 + g * 8;
    float4 wa = *(const float4*)wp;
    float4 wb = *(const float4*)(wp + 4);
    short8 bf = cvt8(wa, wb);
    #pragma unroll
    for (int t = 0; t < 4; ++t) {
      short8 af = *(const short8*)(A + (size_t)(col + t * 16) * H + k0 + g * 8);
      acc[t] = __builtin_amdgcn_mfma_f32_16x16x32_bf16(af, bf, acc[t], 0, 0, 0);
    }
  }

  if (wid) {
    #pragma unroll
    for (int t = 0; t < 4; ++t)
      #pragma unroll
      for (int r = 0; r < 4; ++r) sred[wid - 1][lane][t * 4 + r] = acc[t][r];
  }
  __syncthreads();
  if (wid == 0) {
    float bv = bias[j];
    #pragma unroll
    for (int t = 0; t < 4; ++t)
      #pragma unroll
      for (int r = 0; r < 4; ++r) {
        float s = acc[t][r] + sred[0][lane][t * 4 + r] + sred[1][lane][t * 4 + r] +
                  sred[2][lane][t * 4 + r];
        int brow = t * 16 + g * 4 + r;
        out[brow * H3 + j] = s + bv;
      }
  }
}

// ---------------- K8: GRU combine + build A (bf16) = [mb, ctx] ----------------
__global__ __launch_bounds__(256) void k_gru_combine(
    const float* __restrict__ gi, const float* __restrict__ gh,
    const float* __restrict__ h1, const float* __restrict__ ctx,
    short* __restrict__ Abf) {
  int idx = blockIdx.x * 256 + threadIdx.x;  // B*H
  int b = idx >> 9, h = idx & 511;
  const float* gib = gi + b * H3;
  const float* ghb = gh + b * H3;
  float r = sigf(gib[h] + ghb[h]);
  float z = sigf(gib[H + h] + ghb[H + h]);
  float n = tanhf(gib[2 * H + h] + r * ghb[2 * H + h]);
  float mb = (1.f - z) * n + z * h1[idx];
  Abf[b * H2 + h] = bf16c(mb);
  Abf[b * H2 + H + h] = bf16c(ctx[idx]);
}

// ---------------- K9: logits = A @ W^T + bias — R6 pipeline, FAT 4-wave compute ----------------
// grid NB=786 x 256 thr (4 waves), ~4 blocks/CU (33 KB LDS). Per block: 64 vocab x 64 batch,
// BK=64, 16 K-steps. Wave w: vhalf=w&1 (32 vocab), bhalf=w>>1 (32 batch), acc[2][2].
// Per K-step per block: 32 ds_read_b128 + 32 MFMA (1.0 reads/MFMA vs R6's 1.5).
// Staging identical in pattern to R6 (reg-load f32 W + bf16 A, cvt, swizzled ds_write,
// issue-early/write-late, one barrier per K-step).
__global__ __launch_bounds__(256) void k_out_gemm_mfma(
    const short* __restrict__ Abf, const float* __restrict__ W,
    const float* __restrict__ bias, float* __restrict__ out,
    float* __restrict__ pm, float* __restrict__ ps) {
  __shared__ short8 Wl[1024];   // 2 stages * 64 rows * 8 chunks = 16 KB
  __shared__ short8 Al[1024];   // 16 KB
  __shared__ float spm[4][32];
  __shared__ float sps[4][32];
  const int tid = threadIdx.x;
  const int lane = tid & 63, wid = tid >> 6;
  const int v0 = blockIdx.x * 64;

  // staging role: row sr (0..63), quarter sj (0..3) -> chunks 2sj, 2sj+1
  const int sr = tid >> 2, sj = tid & 3;
  const int sx = sr & 7;
  const int sidx0 = sr * 8 + ((2 * sj) ^ sx);
  const int sidx1 = sr * 8 + ((2 * sj + 1) ^ sx);
  int vr = v0 + sr; if (vr >= V) vr = V - 1;
  const float* wsrc = W + (size_t)vr * H2 + sj * 16;
  const short* asrc = Abf + (size_t)sr * H2 + sj * 16;

  // compute role
  const int col = lane & 15, g = lane >> 4;
  const int vhalf = wid & 1, bhalf = wid >> 1;
  const int wr0 = vhalf * 32 + col, wr1 = wr0 + 16;
  const int ar0 = bhalf * 32 + col, ar1 = ar0 + 16;

  f32x4 acc00 = (f32x4)(0.f), acc01 = (f32x4)(0.f);
  f32x4 acc10 = (f32x4)(0.f), acc11 = (f32x4)(0.f);

  // prologue: stage kt=0 into buf 0
  {
    float4 wa0 = *(const float4*)(wsrc);
    float4 wb0 = *(const float4*)(wsrc + 4);
    float4 wa1 = *(const float4*)(wsrc + 8);
    float4 wb1 = *(const float4*)(wsrc + 12);
    short8 av0 = *(const short8*)(asrc);
    short8 av1 = *(const short8*)(asrc + 8);
    Wl[sidx0] = cvt8(wa0, wb0);
    Wl[sidx1] = cvt8(wa1, wb1);
    Al[sidx0] = av0;
    Al[sidx1] = av1;
  }
  __syncthreads();

  int cur = 0;
  for (int kt = 0; kt < 16; ++kt) {
    // issue next-stage loads early
    float4 nwa0, nwb0, nwa1, nwb1;
    short8 nav0, nav1;
    if (kt < 15) {
      const float* wn = wsrc + (kt + 1) * 64;
      nwa0 = *(const float4*)(wn);
      nwb0 = *(const float4*)(wn + 4);
      nwa1 = *(const float4*)(wn + 8);
      nwb1 = *(const float4*)(wn + 12);
      const short* an = asrc + (kt + 1) * 64;
      nav0 = *(const short8*)(an);
      nav1 = *(const short8*)(an + 8);
    }
    // compute from buf[cur]
    {
      const short8* Wb = Wl + cur * 512;
      const short8* Ab = Al + cur * 512;
      #pragma unroll
      for (int kw = 0; kw < 2; ++kw) {
        int c = kw * 4 + g;
        short8 bf0 = Wb[wr0 * 8 + (c ^ (wr0 & 7))];
        short8 bf1 = Wb[wr1 * 8 + (c ^ (wr1 & 7))];
        short8 af0 = Ab[ar0 * 8 + (c ^ (ar0 & 7))];
        short8 af1 = Ab[ar1 * 8 + (c ^ (ar1 & 7))];
        acc00 = __builtin_amdgcn_mfma_f32_16x16x32_bf16(af0, bf0, acc00, 0, 0, 0);
        acc01 = __builtin_amdgcn_mfma_f32_16x16x32_bf16(af0, bf1, acc01, 0, 0, 0);
        acc10 = __builtin_amdgcn_mfma_f32_16x16x32_bf16(af1, bf0, acc10, 0, 0, 0);
        acc11 = __builtin_amdgcn_mfma_f32_16x16x32_bf16(af1, bf1, acc11, 0, 0, 0);
      }
    }
    // write next stage to buf[cur^1]
    if (kt < 15) {
      Wl[(cur ^ 1) * 512 + sidx0] = cvt8(nwa0, nwb0);
      Wl[(cur ^ 1) * 512 + sidx1] = cvt8(nwa1, nwb1);
      Al[(cur ^ 1) * 512 + sidx0] = nav0;
      Al[(cur ^ 1) * 512 + sidx1] = nav1;
      __syncthreads();
      cur ^= 1;
    }
  }

  // epilogue: store + fused per-block LSE partials
  #pragma unroll
  for (int ai = 0; ai < 2; ++ai) {
    #pragma unroll
    for (int r = 0; r < 4; ++r) {
      int b = bhalf * 32 + ai * 16 + g * 4 + r;
      float mx[2], ee[2];
      #pragma unroll
      for (int u = 0; u < 2; ++u) {
        int v = v0 + vhalf * 32 + u * 16 + col;
        f32x4 a = ai ? (u ? acc11 : acc10) : (u ? acc01 : acc00);
        float bv = (v < V) ? bias[v] : 0.f;
        float x = a[r] + bv;
        if (v < V) out[(size_t)b * V + v] = x;
        float xm = (v < V) ? x : -1e30f;
        float m = xm;
        #pragma unroll
        for (int off = 1; off < 16; off <<= 1) m = fmaxf(m, __shfl_xor(m, off));
        float e = (v < V) ? expf(xm - m) : 0.f;
        #pragma unroll
        for (int off = 1; off < 16; off <<= 1) e += __shfl_xor(e, off);
        mx[u] = m; ee[u] = e;
      }
      float m = fmaxf(mx[0], mx[1]);
      float e = ee[0] * expf(mx[0] - m) + ee[1] * expf(mx[1] - m);
      if (col == 0) {
        spm[wid][ai * 16 + g * 4 + r] = m;
        sps[wid][ai * 16 + g * 4 + r] = e;
      }
    }
  }
  __syncthreads();
  if (tid < 64) {
    int b = tid;
    int w0 = (b >> 5) * 2;       // waves with this bhalf (vhalf = 0,1)
    int bl = b & 31;
    float m1 = spm[w0][bl],     s1 = sps[w0][bl];
    float m2 = spm[w0 + 1][bl], s2 = sps[w0 + 1][bl];
    float nm = fmaxf(m1, m2);
    float s = s1 * expf(m1 - nm) + s2 * expf(m2 - nm);
    pm[(size_t)b * NB + blockIdx.x] = nm;
    ps[(size_t)b * NB + blockIdx.x] = s;
  }
}

// ---------------- K10: combine partials -> lse[b] ----------------
__global__ __launch_bounds__(256) void k_lsm_finalize(
    const float* __restrict__ pm, const float* __restrict__ ps,
    float* __restrict__ lse) {
  int b = blockIdx.x, tid = threadIdx.x;
  float m = -1e30f, s = 0.f;
  for (int gq = tid; gq < NB; gq += 256) {
    float m2 = pm[(size_t)b * NB + gq], s2 = ps[(size_t)b * NB + gq];
    float nm = fmaxf(m, m2);
    s = s * expf(m - nm) + s2 * expf(m2 - nm);
    m = nm;
  }
  __shared__ float sm[256], ss[256];
  sm[tid] = m; ss[tid] = s;
  __syncthreads();
  for (int off = 128; off > 0; off >>= 1) {
    if (tid < off) {
      float m1 = sm[tid], s1 = ss[tid];
      float m2 = sm[tid + off], s2 = ss[tid + off];
      float nm = fmaxf(m1, m2);
      sm[tid] = nm;
      ss[tid] = s1 * expf(m1 - nm) + s2 * expf(m2 - nm);
    }
    __syncthreads();
  }
  if (tid == 0) lse[b] = sm[0] + logf(ss[0]);
}

// ---------------- K11: out -= lse[b]. grid (50, B) ----------------
__global__ __launch_bounds__(256) void k_lsm_apply(
    float* __restrict__ out, const float* __restrict__ lse) {
  int b = blockIdx.y, tid = threadIdx.x;
  float l = lse[b];
  int v = blockIdx.x * 1024 + tid * 4;
  float* row = out + (size_t)b * V;
  if (v + 3 < V) {
    float4 x = *(const float4*)(row + v);
    x.x -= l; x.y -= l; x.z -= l; x.w -= l;
    *(float4*)(row + v) = x;
  } else {
    for (int i = 0; i < 4 && v + i < V; ++i) row[v + i] -= l;
  }
}

extern "C" void kernel_launch(void* const* d_in, const int* in_sizes, int n_in,
                              void* d_out, int out_size, void* d_ws, size_t ws_size,
                              hipStream_t stream) {
  const float* h0    = (const float*)d_in[0];
  const float* c0    = (const float*)d_in[1];
  const float* ctx   = (const float*)d_in[2];
  const float* emb   = (const float*)d_in[3];
  const float* m_emb = (const float*)d_in[4];
  const float* c_emb = (const float*)d_in[5];
  const float* lWih  = (const float*)d_in[6];
  const float* lWhh  = (const float*)d_in[7];
  const float* lbih  = (const float*)d_in[8];
  const float* lbhh  = (const float*)d_in[9];
  const float* gWih  = (const float*)d_in[10];
  const float* gWhh  = (const float*)d_in[11];
  const float* gbih  = (const float*)d_in[12];
  const float* gbhh  = (const float*)d_in[13];
  const float* aW    = (const float*)d_in[14];
  const float* ab    = (const float*)d_in[15];
  const float* oW    = (const float*)d_in[16];
  const float* ob    = (const float*)d_in[17];
  const int* ids     = (const int*)d_in[18];
  const int* mt      = (const int*)d_in[19];

  float* out = (float*)d_out;
  float* h1  = out + (size_t)B * V;
  float* c1  = h1 + B * H;

  // Workspace layout — offsets in FLOAT units; bf16 buffers counted as shorts/2 floats.
  float* ws    = (float*)d_ws;
  short* Albf  = (short*)ws;                   // 64*1536 shorts = 49152 fl
  float* gates = ws + 49152;                   // B*H4 = 131072 fl
  short* h1bf  = (short*)(gates + B * H4);     // 64*512 shorts = 16384 fl
  float* attn  = gates + B * H4 + 16384;       // B*M = 12800 fl
  float* attnd = attn + B * M;                 // 12800 fl
  float* mcp   = attnd + B * M;                // 4*B*H = 131072 fl
  short* mcbf  = (short*)(mcp + 4 * B * H);    // 64*512 shorts = 16384 fl
  float* gi    = mcp + 4 * B * H + 16384;      // B*H3 = 98304 fl
  float* gh    = gi + B * H3;                  // 98304 fl
  short* Abf   = (short*)(gh + B * H3);        // 64*1024 shorts = 32768 fl
  float* pm    = gh + B * H3 + 32768;          // B*NB = 50304 fl
  float* ps    = pm + (size_t)B * NB;          // 50304 fl
  float* lse   = ps + (size_t)B * NB;          // 64 fl

  dim3 g1(6, B);
  k_build_A<<<g1, 256, 0, stream>>>(emb, ctx, h0, ids, Albf);
  k_lstm_gates_mfma<<<128, 256, 0, stream>>>(Albf, lWih, lWhh, lbih, lbhh, gates);
  k_lstm_cell<<<(B * H) / 256, 256, 0, stream>>>(gates, c0, h1, c1, h1bf);
  k_attn_scores<<<(M * B) / 4, 256, 0, stream>>>(m_emb, mt, h1, attn);
  k_attn_lin_lsm<<<B, 256, 0, stream>>>(attn, aW, ab, attnd);
  dim3 g6(B, 4);
  k_mem_ctx_partial<<<g6, 256, 0, stream>>>(c_emb, mt, attnd, mcp);
  k_mem_ctx_reduce<<<(B * H) / 256, 256, 0, stream>>>(mcp, mcbf);
  k_gru_gates_mfma<<<192, 256, 0, stream>>>(mcbf, h1bf, gWih, gWhh, gbih, gbhh, gi, gh);
  k_gru_combine<<<(B * H) / 256, 256, 0, stream>>>(gi, gh, h1, ctx, Abf);
  k_out_gemm_mfma<<<NB, 256, 0, stream>>>(Abf, oW, ob, out, pm, ps);
  k_lsm_finalize<<<B, 256, 0, stream>>>(pm, ps, lse);
  dim3 g11(50, B);
  k_lsm_apply<<<g11, 256, 0, stream>>>(out, lse);
}

// Round 13
// 110.604 us; speedup vs baseline: 1.3644x; 1.0618x over previous
//
#include <hip/hip_runtime.h>
#include <math.h>

#define B 64
#define H 512
#define V 50257
#define M 200
#define H2 1024
#define H3 1536
#define H4 2048
#define NB 786             // ceil(V/64) = out-GEMM blocks

typedef short short8 __attribute__((ext_vector_type(8)));
typedef float f32x4 __attribute__((ext_vector_type(4)));

__device__ __forceinline__ float sigf(float x) { return 1.f / (1.f + expf(-x)); }

// f32 -> bf16 (RNE) as raw short
__device__ __forceinline__ short bf16c(float f) {
  unsigned u = __builtin_bit_cast(unsigned, f);
  unsigned r = u + 0x7fffu + ((u >> 16) & 1u);
  return (short)(r >> 16);
}

__device__ __forceinline__ short8 cvt8(float4 a, float4 b) {
  short8 w;
  w[0] = bf16c(a.x); w[1] = bf16c(a.y); w[2] = bf16c(a.z); w[3] = bf16c(a.w);
  w[4] = bf16c(b.x); w[5] = bf16c(b.y); w[6] = bf16c(b.z); w[7] = bf16c(b.w);
  return w;
}

// ---------------- K1: A_lstm[b][k] = [relu(emb[ids[b]]) | ctx[b] | h0[b]] (bf16) ----------------
__global__ __launch_bounds__(256) void k_build_A(
    const float* __restrict__ emb, const float* __restrict__ ctx,
    const float* __restrict__ h0, const int* __restrict__ ids,
    short* __restrict__ A) {
  int k = blockIdx.x * 256 + threadIdx.x;   // 0..1535
  int b = blockIdx.y;
  float v;
  if (k < 512) {
    v = emb[(size_t)ids[b] * H + k];
    v = v > 0.f ? v : 0.f;
  } else if (k < 1024) {
    v = ctx[b * H + (k - 512)];
  } else {
    v = h0[b * H + (k - 1024)];
  }
  A[b * H3 + k] = bf16c(v);
}

// ---------------- K2: LSTM gates via MFMA. grid 128 (16 j-cols each), 4 waves k-split ----------------
__global__ __launch_bounds__(256) void k_lstm_gates_mfma(
    const short* __restrict__ A, const float* __restrict__ W_ih,
    const float* __restrict__ W_hh, const float* __restrict__ b_ih,
    const float* __restrict__ b_hh, float* __restrict__ gates) {
  __shared__ float sred[3][64][16];
  const int tid = threadIdx.x;
  const int lane = tid & 63, wid = tid >> 6;
  const int col = lane & 15, g = lane >> 4;
  const int j = blockIdx.x * 16 + col;      // gate-row 0..2047
  const int kbase = wid * 384;

  f32x4 acc[4];
  #pragma unroll
  for (int t = 0; t < 4; ++t) acc[t] = (f32x4)(0.f);

  #pragma unroll 2
  for (int it = 0; it < 12; ++it) {
    int k0 = kbase + it * 32;
    const float* wp;
    if (k0 < 1024) wp = W_ih + (size_t)j * H2 + k0 + g * 8;
    else           wp = W_hh + (size_t)j * H + (k0 - 1024) + g * 8;
    float4 wa = *(const float4*)wp;
    float4 wb = *(const float4*)(wp + 4);
    short8 bf = cvt8(wa, wb);
    #pragma unroll
    for (int t = 0; t < 4; ++t) {
      short8 af = *(const short8*)(A + (size_t)(col + t * 16) * H3 + k0 + g * 8);
      acc[t] = __builtin_amdgcn_mfma_f32_16x16x32_bf16(af, bf, acc[t], 0, 0, 0);
    }
  }

  if (wid) {
    #pragma unroll
    for (int t = 0; t < 4; ++t)
      #pragma unroll
      for (int r = 0; r < 4; ++r) sred[wid - 1][lane][t * 4 + r] = acc[t][r];
  }
  __syncthreads();
  if (wid == 0) {
    float bias = b_ih[j] + b_hh[j];
    #pragma unroll
    for (int t = 0; t < 4; ++t)
      #pragma unroll
      for (int r = 0; r < 4; ++r) {
        float s = acc[t][r] + sred[0][lane][t * 4 + r] + sred[1][lane][t * 4 + r] +
                  sred[2][lane][t * 4 + r];
        int brow = t * 16 + g * 4 + r;
        gates[brow * H4 + j] = s + bias;
      }
  }
}

// ---------------- K3: LSTM cell elementwise (+ h1 bf16 copy) ----------------
__global__ __launch_bounds__(256) void k_lstm_cell(
    const float* __restrict__ gates, const float* __restrict__ c0,
    float* __restrict__ h1, float* __restrict__ c1, short* __restrict__ h1bf) {
  int idx = blockIdx.x * 256 + threadIdx.x;  // B*H
  int b = idx >> 9, h = idx & 511;
  const float* g = gates + b * H4;
  float gi = g[h], gf = g[H + h], gg = g[2 * H + h], go = g[3 * H + h];
  float c = sigf(gf) * c0[idx] + sigf(gi) * tanhf(gg);
  c1[idx] = c;
  float hv = sigf(go) * tanhf(c);
  h1[idx] = hv;
  h1bf[idx] = bf16c(hv);
}

// ---------------- K4: attn[b][m] = m_emb[mt[m][b]] . h1[b] ----------------
__global__ __launch_bounds__(256) void k_attn_scores(
    const float* __restrict__ m_emb, const int* __restrict__ mt,
    const float* __restrict__ h1, float* __restrict__ attn) {
  int wave = (blockIdx.x * 256 + threadIdx.x) >> 6;
  int lane = threadIdx.x & 63;
  int m = wave >> 6, b = wave & 63;
  int row = mt[m * B + b];
  const float4* e = (const float4*)(m_emb + (size_t)row * H);
  const float4* hv = (const float4*)(h1 + b * H);
  float4 a0 = e[lane], a1 = e[64 + lane];
  float4 b0 = hv[lane], b1 = hv[64 + lane];
  float acc = a0.x * b0.x + a0.y * b0.y + a0.z * b0.z + a0.w * b0.w +
              a1.x * b1.x + a1.y * b1.y + a1.z * b1.z + a1.w * b1.w;
  for (int off = 32; off > 0; off >>= 1) acc += __shfl_down(acc, off);
  if (lane == 0) attn[b * M + m] = acc;
}

// ---------------- K5: attn2 = attn @ attn_W^T + attn_b; log_softmax ----------------
__global__ __launch_bounds__(256) void k_attn_lin_lsm(
    const float* __restrict__ attn, const float* __restrict__ attn_W,
    const float* __restrict__ attn_b, float* __restrict__ attn_d) {
  __shared__ float arow[M];
  __shared__ float vals[256];
  __shared__ float red[256];
  int b = blockIdx.x, tid = threadIdx.x;
  if (tid < M) arow[tid] = attn[b * M + tid];
  __syncthreads();
  float v = -1e30f;
  if (tid < M) {
    const float* w = attn_W + tid * M;
    float a0 = attn_b[tid], a1 = 0.f;
    for (int m = 0; m < M; m += 2) {
      a0 = fmaf(arow[m], w[m], a0);
      a1 = fmaf(arow[m + 1], w[m + 1], a1);
    }
    v = a0 + a1;
  }
  vals[tid] = v;
  red[tid] = v;
  __syncthreads();
  for (int off = 128; off > 0; off >>= 1) {
    if (tid < off) red[tid] = fmaxf(red[tid], red[tid + off]);
    __syncthreads();
  }
  float mx = red[0];
  __syncthreads();
  red[tid] = (tid < M) ? expf(vals[tid] - mx) : 0.f;
  __syncthreads();
  for (int off = 128; off > 0; off >>= 1) {
    if (tid < off) red[tid] += red[tid + off];
    __syncthreads();
  }
  float lse = mx + logf(red[0]);
  if (tid < M) attn_d[b * M + tid] = vals[tid] - lse;
}

// ---------------- K6: memory_context partial sums over 4 m-chunks of 50 ----------------
__global__ __launch_bounds__(256) void k_mem_ctx_partial(
    const float* __restrict__ c_emb, const int* __restrict__ mt,
    const float* __restrict__ attn_d, float* __restrict__ mcp) {
  int b = blockIdx.x;     // 64
  int chunk = blockIdx.y; // 4
  int tid = threadIdx.x;  // 256
  __shared__ int rows[50];
  __shared__ float w[50];
  if (tid < 50) {
    int m = chunk * 50 + tid;
    rows[tid] = mt[m * B + b];
    w[tid] = attn_d[b * M + m];
  }
  __syncthreads();
  float acc0 = 0.f, acc1 = 0.f;
  #pragma unroll 5
  for (int i = 0; i < 50; ++i) {
    const float* e = c_emb + (size_t)rows[i] * H;
    acc0 = fmaf(w[i], e[tid], acc0);
    acc1 = fmaf(w[i], e[256 + tid], acc1);
  }
  mcp[(chunk * B + b) * H + tid] = acc0;
  mcp[(chunk * B + b) * H + 256 + tid] = acc1;
}

// K6b: reduce partials -> mc bf16
__global__ __launch_bounds__(256) void k_mem_ctx_reduce(
    const float* __restrict__ mcp, short* __restrict__ mcbf) {
  int idx = blockIdx.x * 256 + threadIdx.x;  // B*H
  float s = 0.f;
  for (int c = 0; c < 4; ++c) s += mcp[c * (B * H) + idx];
  mcbf[idx] = bf16c(s);
}

// ---------------- K7: GRU gates via MFMA. grid 192: half (gi/gh) x 96 col-tiles ----------------
__global__ __launch_bounds__(256) void k_gru_gates_mfma(
    const short* __restrict__ mcbf, const short* __restrict__ h1bf,
    const float* __restrict__ W_ih, const float* __restrict__ W_hh,
    const float* __restrict__ b_ih, const float* __restrict__ b_hh,
    float* __restrict__ gi, float* __restrict__ gh) {
  __shared__ float sred[3][64][16];
  const int tid = threadIdx.x;
  const int lane = tid & 63, wid = tid >> 6;
  const int col = lane & 15, g = lane >> 4;
  const int half = blockIdx.x / 96;
  const int j = (blockIdx.x % 96) * 16 + col;   // 0..1535
  const short* A = half ? h1bf : mcbf;
  const float* W = half ? W_hh : W_ih;
  const float* bias = half ? b_hh : b_ih;
  float* out = half ? gh : gi;
  const int kbase = wid * 128;

  f32x4 acc[4];
  #pragma unroll
  for (int t = 0; t < 4; ++t) acc[t] = (f32x4)(0.f);

  #pragma unroll
  for (int it = 0; it < 4; ++it) {
    int k0 = kbase + it * 32;
    const float* wp = W + (size_t)j * H + k0 + g * 8;
    float4 wa = *(const float4*)wp;
    float4 wb = *(const float4*)(wp + 4);
    short8 bf = cvt8(wa, wb);
    #pragma unroll
    for (int t = 0; t < 4; ++t) {
      short8 af = *(const short8*)(A + (size_t)(col + t * 16) * H + k0 + g * 8);
      acc[t] = __builtin_amdgcn_mfma_f32_16x16x32_bf16(af, bf, acc[t], 0, 0, 0);
    }
  }

  if (wid) {
    #pragma unroll
    for (int t = 0; t < 4; ++t)
      #pragma unroll
      for (int r = 0; r < 4; ++r) sred[wid - 1][lane][t * 4 + r] = acc[t][r];
  }
  __syncthreads();
  if (wid == 0) {
    float bv = bias[j];
    #pragma unroll
    for (int t = 0; t < 4; ++t)
      #pragma unroll
      for (int r = 0; r < 4; ++r) {
        float s = acc[t][r] + sred[0][lane][t * 4 + r] + sred[1][lane][t * 4 + r] +
                  sred[2][lane][t * 4 + r];
        int brow = t * 16 + g * 4 + r;
        out[brow * H3 + j] = s + bv;
      }
  }
}

// ---------------- K8: GRU combine + build A (bf16) = [mb, ctx] ----------------
__global__ __launch_bounds__(256) void k_gru_combine(
    const float* __restrict__ gi, const float* __restrict__ gh,
    const float* __restrict__ h1, const float* __restrict__ ctx,
    short* __restrict__ Abf) {
  int idx = blockIdx.x * 256 + threadIdx.x;  // B*H
  int b = idx >> 9, h = idx & 511;
  const float* gib = gi + b * H3;
  const float* ghb = gh + b * H3;
  float r = sigf(gib[h] + ghb[h]);
  float z = sigf(gib[H + h] + ghb[H + h]);
  float n = tanhf(gib[2 * H + h] + r * ghb[2 * H + h]);
  float mb = (1.f - z) * n + z * h1[idx];
  Abf[b * H2 + h] = bf16c(mb);
  Abf[b * H2 + H + h] = bf16c(ctx[idx]);
}

// ---------------- K9: logits = A @ W^T + bias — LDS-staged, DEPTH-3 pipelined MFMA ----------------
// Best-measured session configuration (R7: 109.63 µs total, GEMM ~70 µs).
// grid NB=786 x 512 threads (8 waves). Per block: 64 vocab rows x 64 batch, BK=64, 16 K-steps.
// At iter kt: issue global loads for stage kt+2, compute stage kt from LDS[cur],
// then ds_write stage kt+1 (issued a full iter ago) to LDS[cur^1]. Two static register
// stage-sets (a/b) — parity fully unrolled so indices are compile-time.
__global__ __launch_bounds__(512) void k_out_gemm_mfma(
    const short* __restrict__ Abf, const float* __restrict__ W,
    const float* __restrict__ bias, float* __restrict__ out,
    float* __restrict__ pm, float* __restrict__ ps) {
  __shared__ short8 Wl[1024];   // 2 stages * 64 rows * 8 chunks = 16 KB
  __shared__ short8 Al[1024];   // 16 KB
  __shared__ float spm[8][32];
  __shared__ float sps[8][32];
  const int tid = threadIdx.x;
  const int v0 = blockIdx.x * 64;

  // staging role: row sr (0..63), chunk sj (0..7); 32B W + 16B A per stage per thread
  const int sr = tid >> 3, sj = tid & 7;
  const int sidx = sr * 8 + (sj ^ (sr & 7));
  int vr = v0 + sr; if (vr >= V) vr = V - 1;
  const float* wsrc = W + (size_t)vr * H2 + sj * 8;
  const short8* asrc = (const short8*)(Abf + sr * H2 + sj * 8);

  // compute role
  const int lane = tid & 63, wid = tid >> 6;
  const int col = lane & 15, g = lane >> 4;
  const int ct = wid & 3, bh = wid >> 2;
  const int wrow = ct * 16 + col;
  const int a0r = bh * 32 + col;
  const int a1r = a0r + 16;

  f32x4 acc0 = (f32x4)(0.f), acc1 = (f32x4)(0.f);

  float4 wa_a, wb_a, wa_b, wb_b;
  short8 av_a, av_b;

  // prologue: issue stage 0 (set a) and stage 1 (set b); write stage 0
  wa_a = *(const float4*)(wsrc);
  wb_a = *(const float4*)(wsrc + 4);
  av_a = asrc[0];
  wa_b = *(const float4*)(wsrc + 64);
  wb_b = *(const float4*)(wsrc + 68);
  av_b = asrc[8];
  Wl[sidx] = cvt8(wa_a, wb_a);
  Al[sidx] = av_a;
  __syncthreads();

  int cur = 0;
  #pragma unroll
  for (int kp = 0; kp < 8; ++kp) {
    // ---- even iter kt0 = 2kp: LDS[cur]=stage kt0; regs_b = stage kt0+1 (in flight) ----
    if (2 * kp + 2 < 16) {   // issue stage kt0+2 -> set a
      wa_a = *(const float4*)(wsrc + (2 * kp + 2) * 64);
      wb_a = *(const float4*)(wsrc + (2 * kp + 2) * 64 + 4);
      av_a = asrc[(2 * kp + 2) * 8];
    }
    {
      const short8* Wb = Wl + cur * 512;
      const short8* Ab = Al + cur * 512;
      #pragma unroll
      for (int kw = 0; kw < 2; ++kw) {
        int c = kw * 4 + g;
        short8 bf  = Wb[wrow * 8 + (c ^ (wrow & 7))];
        short8 af0 = Ab[a0r * 8 + (c ^ (a0r & 7))];
        short8 af1 = Ab[a1r * 8 + (c ^ (a1r & 7))];
        acc0 = __builtin_amdgcn_mfma_f32_16x16x32_bf16(af0, bf, acc0, 0, 0, 0);
        acc1 = __builtin_amdgcn_mfma_f32_16x16x32_bf16(af1, bf, acc1, 0, 0, 0);
      }
    }
    // write stage kt0+1 (set b) -> LDS[cur^1]   (always: kt0+1 = 2kp+1 <= 15)
    Wl[(cur ^ 1) * 512 + sidx] = cvt8(wa_b, wb_b);
    Al[(cur ^ 1) * 512 + sidx] = av_b;
    __syncthreads();
    cur ^= 1;

    // ---- odd iter kt1 = 2kp+1: regs_a = stage kt1+1 (in flight) ----
    if (2 * kp + 3 < 16) {   // issue stage kt1+2 -> set b
      wa_b = *(const float4*)(wsrc + (2 * kp + 3) * 64);
      wb_b = *(const float4*)(wsrc + (2 * kp + 3) * 64 + 4);
      av_b = asrc[(2 * kp + 3) * 8];
    }
    {
      const short8* Wb = Wl + cur * 512;
      const short8* Ab = Al + cur * 512;
      #pragma unroll
      for (int kw = 0; kw < 2; ++kw) {
        int c = kw * 4 + g;
        short8 bf  = Wb[wrow * 8 + (c ^ (wrow & 7))];
        short8 af0 = Ab[a0r * 8 + (c ^ (a0r & 7))];
        short8 af1 = Ab[a1r * 8 + (c ^ (a1r & 7))];
        acc0 = __builtin_amdgcn_mfma_f32_16x16x32_bf16(af0, bf, acc0, 0, 0, 0);
        acc1 = __builtin_amdgcn_mfma_f32_16x16x32_bf16(af1, bf, acc1, 0, 0, 0);
      }
    }
    if (2 * kp + 2 < 16) {   // write stage kt1+1 (set a); skip at kp=7 (stage 16)
      Wl[(cur ^ 1) * 512 + sidx] = cvt8(wa_a, wb_a);
      Al[(cur ^ 1) * 512 + sidx] = av_a;
      __syncthreads();
      cur ^= 1;
    }
  }

  // epilogue: store + fused per-block LSE partials
  const int v = v0 + ct * 16 + col;
  const float bv = (v < V) ? bias[v] : 0.f;
  #pragma unroll
  for (int ai = 0; ai < 2; ++ai) {
    f32x4 a = ai ? acc1 : acc0;
    #pragma unroll
    for (int r = 0; r < 4; ++r) {
      int b = bh * 32 + ai * 16 + g * 4 + r;
      float x = a[r] + bv;
      if (v < V) out[(size_t)b * V + v] = x;
      float xm = (v < V) ? x : -1e30f;
      float mx = xm;
      #pragma unroll
      for (int off = 1; off < 16; off <<= 1) mx = fmaxf(mx, __shfl_xor(mx, off));
      float e = (v < V) ? expf(xm - mx) : 0.f;
      #pragma unroll
      for (int off = 1; off < 16; off <<= 1) e += __shfl_xor(e, off);
      if (col == 0) {
        spm[wid][ai * 16 + g * 4 + r] = mx;
        sps[wid][ai * 16 + g * 4 + r] = e;
      }
    }
  }
  __syncthreads();
  if (tid < 64) {
    int b = tid;
    int wbase = (b >> 5) * 4;
    int bl = b & 31;
    float m = spm[wbase][bl], s = sps[wbase][bl];
    #pragma unroll
    for (int w = 1; w < 4; ++w) {
      float m2 = spm[wbase + w][bl], s2 = sps[wbase + w][bl];
      float nm = fmaxf(m, m2);
      s = s * expf(m - nm) + s2 * expf(m2 - nm);
      m = nm;
    }
    pm[(size_t)b * NB + blockIdx.x] = m;
    ps[(size_t)b * NB + blockIdx.x] = s;
  }
}

// ---------------- K10: combine partials -> lse[b] ----------------
__global__ __launch_bounds__(256) void k_lsm_finalize(
    const float* __restrict__ pm, const float* __restrict__ ps,
    float* __restrict__ lse) {
  int b = blockIdx.x, tid = threadIdx.x;
  float m = -1e30f, s = 0.f;
  for (int gq = tid; gq < NB; gq += 256) {
    float m2 = pm[(size_t)b * NB + gq], s2 = ps[(size_t)b * NB + gq];
    float nm = fmaxf(m, m2);
    s = s * expf(m - nm) + s2 * expf(m2 - nm);
    m = nm;
  }
  __shared__ float sm[256], ss[256];
  sm[tid] = m; ss[tid] = s;
  __syncthreads();
  for (int off = 128; off > 0; off >>= 1) {
    if (tid < off) {
      float m1 = sm[tid], s1 = ss[tid];
      float m2 = sm[tid + off], s2 = ss[tid + off];
      float nm = fmaxf(m1, m2);
      sm[tid] = nm;
      ss[tid] = s1 * expf(m1 - nm) + s2 * expf(m2 - nm);
    }
    __syncthreads();
  }
  if (tid == 0) lse[b] = sm[0] + logf(ss[0]);
}

// ---------------- K11: out -= lse[b]. grid (50, B) ----------------
__global__ __launch_bounds__(256) void k_lsm_apply(
    float* __restrict__ out, const float* __restrict__ lse) {
  int b = blockIdx.y, tid = threadIdx.x;
  float l = lse[b];
  int v = blockIdx.x * 1024 + tid * 4;
  float* row = out + (size_t)b * V;
  if (v + 3 < V) {
    float4 x = *(const float4*)(row + v);
    x.x -= l; x.y -= l; x.z -= l; x.w -= l;
    *(float4*)(row + v) = x;
  } else {
    for (int i = 0; i < 4 && v + i < V; ++i) row[v + i] -= l;
  }
}

extern "C" void kernel_launch(void* const* d_in, const int* in_sizes, int n_in,
                              void* d_out, int out_size, void* d_ws, size_t ws_size,
                              hipStream_t stream) {
  const float* h0    = (const float*)d_in[0];
  const float* c0    = (const float*)d_in[1];
  const float* ctx   = (const float*)d_in[2];
  const float* emb   = (const float*)d_in[3];
  const float* m_emb = (const float*)d_in[4];
  const float* c_emb = (const float*)d_in[5];
  const float* lWih  = (const float*)d_in[6];
  const float* lWhh  = (const float*)d_in[7];
  const float* lbih  = (const float*)d_in[8];
  const float* lbhh  = (const float*)d_in[9];
  const float* gWih  = (const float*)d_in[10];
  const float* gWhh  = (const float*)d_in[11];
  const float* gbih  = (const float*)d_in[12];
  const float* gbhh  = (const float*)d_in[13];
  const float* aW    = (const float*)d_in[14];
  const float* ab    = (const float*)d_in[15];
  const float* oW    = (const float*)d_in[16];
  const float* ob    = (const float*)d_in[17];
  const int* ids     = (const int*)d_in[18];
  const int* mt      = (const int*)d_in[19];

  float* out = (float*)d_out;
  float* h1  = out + (size_t)B * V;
  float* c1  = h1 + B * H;

  // Workspace layout — offsets in FLOAT units; bf16 buffers counted as shorts/2 floats.
  float* ws    = (float*)d_ws;
  short* Albf  = (short*)ws;                   // 64*1536 shorts = 49152 fl
  float* gates = ws + 49152;                   // B*H4 = 131072 fl
  short* h1bf  = (short*)(gates + B * H4);     // 64*512 shorts = 16384 fl
  float* attn  = gates + B * H4 + 16384;       // B*M = 12800 fl
  float* attnd = attn + B * M;                 // 12800 fl
  float* mcp   = attnd + B * M;                // 4*B*H = 131072 fl
  short* mcbf  = (short*)(mcp + 4 * B * H);    // 64*512 shorts = 16384 fl
  float* gi    = mcp + 4 * B * H + 16384;      // B*H3 = 98304 fl
  float* gh    = gi + B * H3;                  // 98304 fl
  short* Abf   = (short*)(gh + B * H3);        // 64*1024 shorts = 32768 fl
  float* pm    = gh + B * H3 + 32768;          // B*NB = 50304 fl
  float* ps    = pm + (size_t)B * NB;          // 50304 fl
  float* lse   = ps + (size_t)B * NB;          // 64 fl

  dim3 g1(6, B);
  k_build_A<<<g1, 256, 0, stream>>>(emb, ctx, h0, ids, Albf);
  k_lstm_gates_mfma<<<128, 256, 0, stream>>>(Albf, lWih, lWhh, lbih, lbhh, gates);
  k_lstm_cell<<<(B * H) / 256, 256, 0, stream>>>(gates, c0, h1, c1, h1bf);
  k_attn_scores<<<(M * B) / 4, 256, 0, stream>>>(m_emb, mt, h1, attn);
  k_attn_lin_lsm<<<B, 256, 0, stream>>>(attn, aW, ab, attnd);
  dim3 g6(B, 4);
  k_mem_ctx_partial<<<g6, 256, 0, stream>>>(c_emb, mt, attnd, mcp);
  k_mem_ctx_reduce<<<(B * H) / 256, 256, 0, stream>>>(mcp, mcbf);
  k_gru_gates_mfma<<<192, 256, 0, stream>>>(mcbf, h1bf, gWih, gWhh, gbih, gbhh, gi, gh);
  k_gru_combine<<<(B * H) / 256, 256, 0, stream>>>(gi, gh, h1, ctx, Abf);
  k_out_gemm_mfma<<<NB, 512, 0, stream>>>(Abf, oW, ob, out, pm, ps);
  k_lsm_finalize<<<B, 256, 0, stream>>>(pm, ps, lse);
  dim3 g11(50, B);
  k_lsm_apply<<<g11, 256, 0, stream>>>(out, lse);
}